// Round 8
// baseline (981.339 us; speedup 1.0000x reference)
//
#include <hip/hip_runtime.h>
#include <stdint.h>

// LightGCNConv: out[row] += x[col] * edge_weight[e]
// x:[N,64] f32, edge_index:[2,E] int32, edge_weight:[E] f32, out:[N,64] f32.
//
// Two-phase binning:
//  1) bin_edges: append each edge as 8B (rowLocal<<17|col, f32 w) into
//     segment (bucket = row>>8, class = blockIdx&7). Dense appends -> each
//     64B line written back once (fixes measured 83MB csr-scatter writeback).
//  2) bucket_acc: one block per 256-row bucket, f32 accumulator in 64KB LDS,
//     bf16 x gather 8-deep pipelined, LDS atomic accumulate, coalesced store.

typedef unsigned long long ull;
typedef int   v4i __attribute__((ext_vector_type(4)));
typedef float v4f __attribute__((ext_vector_type(4)));

#define RB      256      // rows per bucket
#define NCLS    8        // segments per bucket (one per XCD class)
#define CAP     768      // entries per (bucket,class) segment; mean ~510
#define OVF_CAP 65536

__device__ __forceinline__ unsigned short f2bf(float f) {
    union { float f; unsigned int u; } c;
    c.f = f;
    unsigned int lsb = (c.u >> 16) & 1u;
    c.u += 0x7fffu + lsb;
    return (unsigned short)(c.u >> 16);
}
__device__ __forceinline__ float bf2f(unsigned short u) {
    union { unsigned int u; float f; } c;
    c.u = ((unsigned int)u) << 16;
    return c.f;
}

// ---------- convert x -> bf16 ----------
__global__ __launch_bounds__(256) void convert_x(
    const float* __restrict__ x, unsigned short* __restrict__ xb, int n4)
{
    int i = blockIdx.x * 256 + threadIdx.x;
    if (i >= n4) return;
    v4f v = ((const v4f*)x)[i];
    ushort4 o;
    o.x = f2bf(v.x); o.y = f2bf(v.y); o.z = f2bf(v.z); o.w = f2bf(v.w);
    ((ushort4*)xb)[i] = o;
}

// ---------- phase 1: bin edges into (bucket,class) segments ----------
__device__ __forceinline__ void bin_one(
    int row, int col, float w, int cls,
    int* __restrict__ bcnt, ull* __restrict__ seg,
    int* __restrict__ ovf_cnt, int3* __restrict__ ovf)
{
    int b   = row >> 8;            // bucket (RB=256)
    int rl  = row & 255;
    int idx = b * NCLS + cls;
    int pos = atomicAdd(&bcnt[idx], 1);
    if (pos < CAP) {
        ull entry = (((ull)__float_as_uint(w)) << 32) |
                    (unsigned)((rl << 17) | col);
        seg[(size_t)idx * CAP + pos] = entry;
    } else {
        int o = atomicAdd(ovf_cnt, 1);
        if (o < OVF_CAP) ovf[o] = make_int3(row, col, __float_as_int(w));
    }
}

__global__ __launch_bounds__(256) void bin_edges(
    const int* __restrict__ ei, const float* __restrict__ ew,
    int* __restrict__ bcnt, ull* __restrict__ seg,
    int* __restrict__ ovf_cnt, int3* __restrict__ ovf, int E)
{
    int cls = blockIdx.x & 7;
    int e0 = blockIdx.x * 1024 + threadIdx.x * 4;
    if (e0 + 3 < E && (E & 3) == 0) {
        v4i r = __builtin_nontemporal_load((const v4i*)(ei + e0));
        v4i c = __builtin_nontemporal_load((const v4i*)(ei + E + e0));
        v4f w = __builtin_nontemporal_load((const v4f*)(ew + e0));
        bin_one(r.x, c.x, w.x, cls, bcnt, seg, ovf_cnt, ovf);
        bin_one(r.y, c.y, w.y, cls, bcnt, seg, ovf_cnt, ovf);
        bin_one(r.z, c.z, w.z, cls, bcnt, seg, ovf_cnt, ovf);
        bin_one(r.w, c.w, w.w, cls, bcnt, seg, ovf_cnt, ovf);
    } else {
        for (int e = e0; e < E && e < e0 + 4; ++e)
            bin_one(ei[e], ei[E + e], ew[e], cls, bcnt, seg, ovf_cnt, ovf);
    }
}

// ---------- phase 2: one block per bucket, LDS f32 accumulate ----------
__global__ __launch_bounds__(256) void bucket_acc(
    const unsigned short* __restrict__ xb, const int* __restrict__ bcnt,
    const ull* __restrict__ seg, float* __restrict__ out, int N)
{
    __shared__ float acc[RB * 64];       // 64 KB
    int g = blockIdx.x;
    int t = threadIdx.x;
    int wave = t >> 6, lane = t & 63;

    // zero LDS
    v4f z4 = (v4f){0.f, 0.f, 0.f, 0.f};
    v4f* a4 = (v4f*)acc;
    for (int i = t; i < RB * 16; i += 256) a4[i] = z4;
    __syncthreads();

    for (int cls = 0; cls < NCLS; ++cls) {
        int idx = g * NCLS + cls;
        int cnt = bcnt[idx];
        if (cnt > CAP) cnt = CAP;
        const ull* base = seg + (size_t)idx * CAP;

        for (int s = wave * 64; s < cnt; s += 256) {
            int nval = cnt - s;
            if (nval > 64) nval = 64;
            int li = lane < nval ? lane : nval - 1;
            ull ev = __builtin_nontemporal_load(base + s + li);
            unsigned lo = (unsigned)ev;
            unsigned hi = (unsigned)(ev >> 32);

            int j = 0;
            for (; j + 8 <= nval; j += 8) {
                unsigned pk[8]; float w[8], xv[8];
#pragma unroll
                for (int i = 0; i < 8; ++i) {
                    pk[i] = (unsigned)__shfl((int)lo, j + i);
                    w[i]  = __int_as_float(__shfl((int)hi, j + i));
                }
#pragma unroll
                for (int i = 0; i < 8; ++i) {
                    unsigned col = pk[i] & 0x1FFFFu;
                    xv[i] = bf2f(xb[(((size_t)col) << 6) + lane]);
                }
#pragma unroll
                for (int i = 0; i < 8; ++i) {
                    unsigned rl = pk[i] >> 17;
                    unsafeAtomicAdd(&acc[(rl << 6) + lane], xv[i] * w[i]);
                }
            }
            if (j < nval) {      // masked tail group
                unsigned pk[8]; float w[8], xv[8];
#pragma unroll
                for (int i = 0; i < 8; ++i) {
                    int q = (j + i < nval) ? j + i : nval - 1;
                    pk[i] = (unsigned)__shfl((int)lo, q);
                    float ww = __int_as_float(__shfl((int)hi, q));
                    w[i] = (j + i < nval) ? ww : 0.0f;
                }
#pragma unroll
                for (int i = 0; i < 8; ++i) {
                    unsigned col = pk[i] & 0x1FFFFu;
                    xv[i] = bf2f(xb[(((size_t)col) << 6) + lane]);
                }
#pragma unroll
                for (int i = 0; i < 8; ++i) {
                    unsigned rl = pk[i] >> 17;
                    unsafeAtomicAdd(&acc[(rl << 6) + lane], xv[i] * w[i]);
                }
            }
        }
    }
    __syncthreads();

    // write bucket rows out, coalesced 16B stores
    int row0 = g * RB;
    for (int i = t; i < RB * 16; i += 256) {
        int r = i >> 4;
        int gr = row0 + r;
        if (gr < N)
            __builtin_nontemporal_store(a4[i],
                ((v4f*)out) + (size_t)gr * 16 + (i & 15));
    }
}

// ---------- overflow fixup (normally 0 edges) ----------
__global__ __launch_bounds__(256) void ovf_apply(
    const unsigned short* __restrict__ xb, const int* __restrict__ ovf_cnt,
    const int3* __restrict__ ovf, float* __restrict__ out)
{
    int n = *ovf_cnt;
    if (n > OVF_CAP) n = OVF_CAP;
    int wid  = (blockIdx.x * 256 + threadIdx.x) >> 6;
    int lane = threadIdx.x & 63;
    int nw   = gridDim.x * 4;
    for (int o = wid; o < n; o += nw) {
        int3 tt = ovf[o];
        float w = __int_as_float(tt.z);
        float x = bf2f(xb[(((size_t)tt.y) << 6) + lane]);
        atomicAdd(&out[(((size_t)tt.x) << 6) + lane], x * w);
    }
}

// ---------- fallback: direct atomic scatter ----------
__global__ __launch_bounds__(256) void scatter_edges(
    const float* __restrict__ x, const int* __restrict__ ei,
    const float* __restrict__ ew, float* __restrict__ out, int E)
{
    long long idx = (long long)blockIdx.x * 256 + threadIdx.x;
    int e = (int)(idx >> 4);
    if (e >= E) return;
    int j = (int)(idx & 15);
    int row = ei[e];
    int col = ei[E + e];
    float w = ew[e];
    v4f v = *(const v4f*)(x + (((size_t)col) << 6) + (j << 2));
    float* op = out + (((size_t)row) << 6) + (j << 2);
    atomicAdd(op + 0, v.x * w);
    atomicAdd(op + 1, v.y * w);
    atomicAdd(op + 2, v.z * w);
    atomicAdd(op + 3, v.w * w);
}

extern "C" void kernel_launch(void* const* d_in, const int* in_sizes, int n_in,
                              void* d_out, int out_size, void* d_ws, size_t ws_size,
                              hipStream_t stream) {
    const float* x  = (const float*)d_in[0];
    const int*   ei = (const int*)d_in[1];
    const float* ew = (const float*)d_in[2];
    float*       out = (float*)d_out;

    int E = in_sizes[2];
    int N = out_size / 64;
    int NBK = (N + RB - 1) / RB;

    // ws ints: bcnt[NBK*8] | ovf_cnt | pad | ovf[3*OVF_CAP] | xb[N*32] | seg
    size_t bcnt_ints = (size_t)NBK * NCLS;
    size_t ovf_base  = bcnt_ints + 2;
    size_t xb_base   = (ovf_base + 3 * (size_t)OVF_CAP + 3) & ~(size_t)3;
    size_t seg_base  = (xb_base + (size_t)N * 32 + 1) & ~(size_t)1;  // 8B align
    size_t need      = (seg_base + (size_t)NBK * NCLS * CAP * 2) * 4;

    if (ws_size >= need && N <= (1 << 17)) {
        int* w32 = (int*)d_ws;
        int* bcnt = w32;
        int* ovf_cnt = w32 + bcnt_ints;
        int3* ovf = (int3*)(w32 + ovf_base);
        unsigned short* xb = (unsigned short*)(w32 + xb_base);
        ull* seg = (ull*)(w32 + seg_base);

        (void)hipMemsetAsync(w32, 0, (bcnt_ints + 2) * sizeof(int), stream);

        int n4 = (N * 64) / 4;
        convert_x<<<(n4 + 255) / 256, 256, 0, stream>>>(x, xb, n4);

        int nbin = (E + 1023) / 1024;
        bin_edges<<<nbin, 256, 0, stream>>>(ei, ew, bcnt, seg, ovf_cnt, ovf, E);

        bucket_acc<<<NBK, 256, 0, stream>>>(xb, bcnt, seg, out, N);
        ovf_apply<<<64, 256, 0, stream>>>(xb, ovf_cnt, ovf, out);
    } else {
        (void)hipMemsetAsync(out, 0, (size_t)out_size * sizeof(float), stream);
        long long threads = (long long)E * 16;
        scatter_edges<<<(int)((threads + 255) / 256), 256, 0, stream>>>(
            x, ei, ew, out, E);
    }
}

// Round 9
// 841.770 us; speedup vs baseline: 1.1658x; 1.1658x over previous
//
#include <hip/hip_runtime.h>
#include <stdint.h>

// LightGCNConv: out[row] += x[col] * edge_weight[e]
// x:[N,64] f32, edge_index:[2,E] int32, edge_weight:[E] f32, out:[N,64] f32.
//
// Two-phase binning:
//  1) bin_edges: append 8B entries (w<<32 | rl<<17 | col) into segment
//     (bucket = row>>7, class = blockIdx&7). Dense appends -> ~1 writeback/line.
//  2) bucket_acc: one 1024-thread block per 128-row bucket; 32KB LDS f32
//     accumulator; each wave owns half of one class segment; wave-uniform
//     entry loads, 8-deep independent bf16 x gathers, ds_add_f32 accumulate;
//     single coalesced store of the bucket.

typedef unsigned long long ull;
typedef int   v4i __attribute__((ext_vector_type(4)));
typedef float v4f __attribute__((ext_vector_type(4)));

#define RB      128      // rows per bucket
#define NCLS    8
#define CAP     384      // entries per (bucket,class) segment; mean ~256
#define OVF_CAP 65536

__device__ __forceinline__ unsigned short f2bf(float f) {
    union { float f; unsigned int u; } c;
    c.f = f;
    unsigned int lsb = (c.u >> 16) & 1u;
    c.u += 0x7fffu + lsb;
    return (unsigned short)(c.u >> 16);
}
__device__ __forceinline__ float bf2f(unsigned short u) {
    union { unsigned int u; float f; } c;
    c.u = ((unsigned int)u) << 16;
    return c.f;
}

// ---------- convert x -> bf16 ----------
__global__ __launch_bounds__(256) void convert_x(
    const float* __restrict__ x, unsigned short* __restrict__ xb, int n4)
{
    int i = blockIdx.x * 256 + threadIdx.x;
    if (i >= n4) return;
    v4f v = ((const v4f*)x)[i];
    ushort4 o;
    o.x = f2bf(v.x); o.y = f2bf(v.y); o.z = f2bf(v.z); o.w = f2bf(v.w);
    ((ushort4*)xb)[i] = o;
}

// ---------- phase 1: bin edges into (bucket,class) segments ----------
__device__ __forceinline__ void bin_one(
    int row, int col, float w, int cls,
    int* __restrict__ bcnt, ull* __restrict__ seg,
    int* __restrict__ ovf_cnt, int3* __restrict__ ovf)
{
    int b   = row >> 7;            // bucket (RB=128)
    int rl  = row & 127;
    int idx = b * NCLS + cls;
    int pos = atomicAdd(&bcnt[idx], 1);
    if (pos < CAP) {
        ull entry = (((ull)__float_as_uint(w)) << 32) |
                    (unsigned)((rl << 17) | col);
        seg[(size_t)idx * CAP + pos] = entry;
    } else {
        int o = atomicAdd(ovf_cnt, 1);
        if (o < OVF_CAP) ovf[o] = make_int3(row, col, __float_as_int(w));
    }
}

__global__ __launch_bounds__(256) void bin_edges(
    const int* __restrict__ ei, const float* __restrict__ ew,
    int* __restrict__ bcnt, ull* __restrict__ seg,
    int* __restrict__ ovf_cnt, int3* __restrict__ ovf, int E)
{
    int cls = blockIdx.x & 7;
    int e0 = blockIdx.x * 1024 + threadIdx.x * 4;
    if (e0 + 3 < E && (E & 3) == 0) {
        v4i r = __builtin_nontemporal_load((const v4i*)(ei + e0));
        v4i c = __builtin_nontemporal_load((const v4i*)(ei + E + e0));
        v4f w = __builtin_nontemporal_load((const v4f*)(ew + e0));
        bin_one(r.x, c.x, w.x, cls, bcnt, seg, ovf_cnt, ovf);
        bin_one(r.y, c.y, w.y, cls, bcnt, seg, ovf_cnt, ovf);
        bin_one(r.z, c.z, w.z, cls, bcnt, seg, ovf_cnt, ovf);
        bin_one(r.w, c.w, w.w, cls, bcnt, seg, ovf_cnt, ovf);
    } else {
        for (int e = e0; e < E && e < e0 + 4; ++e)
            bin_one(ei[e], ei[E + e], ew[e], cls, bcnt, seg, ovf_cnt, ovf);
    }
}

// ---------- phase 2: one 1024-thread block per bucket ----------
__global__ __launch_bounds__(1024) void bucket_acc(
    const unsigned short* __restrict__ xb, const int* __restrict__ bcnt,
    const ull* __restrict__ seg, float* __restrict__ out, int N)
{
    __shared__ float acc[RB * 64];       // 32 KB
    int g = blockIdx.x;
    int t = threadIdx.x;
    int wave = t >> 6, lane = t & 63;    // 16 waves

    v4f z4 = (v4f){0.f, 0.f, 0.f, 0.f};
    v4f* a4 = (v4f*)acc;
    for (int i = t; i < RB * 16; i += 1024) a4[i] = z4;
    __syncthreads();

    // wave -> (class, half)
    int cls  = wave >> 1;
    int half = wave & 1;
    int idx = g * NCLS + cls;
    int cnt = bcnt[idx];
    if (cnt > CAP) cnt = CAP;
    int h0 = cnt >> 1;
    int p    = half ? h0 : 0;
    int endp = half ? cnt : h0;
    const ull* base = seg + (size_t)idx * CAP;

    for (; p + 8 <= endp; p += 8) {
        ull a[8]; float xv[8];
#pragma unroll
        for (int i = 0; i < 8; ++i)
            a[i] = __builtin_nontemporal_load(base + p + i);
#pragma unroll
        for (int i = 0; i < 8; ++i) {
            unsigned col = (unsigned)a[i] & 0x1FFFFu;
            xv[i] = bf2f(xb[(((size_t)col) << 6) + lane]);
        }
#pragma unroll
        for (int i = 0; i < 8; ++i) {
            unsigned rl = ((unsigned)a[i] >> 17) & 127u;
            float w = __int_as_float((int)(a[i] >> 32));
            atomicAdd(&acc[(rl << 6) + lane], xv[i] * w);
        }
    }
    for (; p < endp; ++p) {              // tail < 8
        ull a = __builtin_nontemporal_load(base + p);
        unsigned col = (unsigned)a & 0x1FFFFu;
        unsigned rl  = ((unsigned)a >> 17) & 127u;
        float w = __int_as_float((int)(a >> 32));
        float xv = bf2f(xb[(((size_t)col) << 6) + lane]);
        atomicAdd(&acc[(rl << 6) + lane], xv * w);
    }
    __syncthreads();

    // write bucket rows out, coalesced 16B stores
    int row0 = g * RB;
    for (int i = t; i < RB * 16; i += 1024) {
        int r = i >> 4;
        int gr = row0 + r;
        if (gr < N)
            __builtin_nontemporal_store(a4[i],
                ((v4f*)out) + (size_t)gr * 16 + (i & 15));
    }
}

// ---------- overflow fixup (normally 0 edges) ----------
__global__ __launch_bounds__(256) void ovf_apply(
    const unsigned short* __restrict__ xb, const int* __restrict__ ovf_cnt,
    const int3* __restrict__ ovf, float* __restrict__ out)
{
    int n = *ovf_cnt;
    if (n > OVF_CAP) n = OVF_CAP;
    int wid  = (blockIdx.x * 256 + threadIdx.x) >> 6;
    int lane = threadIdx.x & 63;
    int nw   = gridDim.x * 4;
    for (int o = wid; o < n; o += nw) {
        int3 tt = ovf[o];
        float w = __int_as_float(tt.z);
        float x = bf2f(xb[(((size_t)tt.y) << 6) + lane]);
        atomicAdd(&out[(((size_t)tt.x) << 6) + lane], x * w);
    }
}

// ---------- fallback: direct atomic scatter ----------
__global__ __launch_bounds__(256) void scatter_edges(
    const float* __restrict__ x, const int* __restrict__ ei,
    const float* __restrict__ ew, float* __restrict__ out, int E)
{
    long long idx = (long long)blockIdx.x * 256 + threadIdx.x;
    int e = (int)(idx >> 4);
    if (e >= E) return;
    int j = (int)(idx & 15);
    int row = ei[e];
    int col = ei[E + e];
    float w = ew[e];
    v4f v = *(const v4f*)(x + (((size_t)col) << 6) + (j << 2));
    float* op = out + (((size_t)row) << 6) + (j << 2);
    atomicAdd(op + 0, v.x * w);
    atomicAdd(op + 1, v.y * w);
    atomicAdd(op + 2, v.z * w);
    atomicAdd(op + 3, v.w * w);
}

extern "C" void kernel_launch(void* const* d_in, const int* in_sizes, int n_in,
                              void* d_out, int out_size, void* d_ws, size_t ws_size,
                              hipStream_t stream) {
    const float* x  = (const float*)d_in[0];
    const int*   ei = (const int*)d_in[1];
    const float* ew = (const float*)d_in[2];
    float*       out = (float*)d_out;

    int E = in_sizes[2];
    int N = out_size / 64;
    int NBK = (N + RB - 1) / RB;

    // ws ints: bcnt[NBK*8] | ovf_cnt | pad | ovf[3*OVF_CAP] | xb[N*32] | seg
    size_t bcnt_ints = (size_t)NBK * NCLS;
    size_t ovf_base  = bcnt_ints + 2;
    size_t xb_base   = (ovf_base + 3 * (size_t)OVF_CAP + 3) & ~(size_t)3;
    size_t seg_base  = (xb_base + (size_t)N * 32 + 1) & ~(size_t)1;  // 8B align
    size_t need      = (seg_base + (size_t)NBK * NCLS * CAP * 2) * 4;

    if (ws_size >= need && N <= (1 << 17)) {
        int* w32 = (int*)d_ws;
        int* bcnt = w32;
        int* ovf_cnt = w32 + bcnt_ints;
        int3* ovf = (int3*)(w32 + ovf_base);
        unsigned short* xb = (unsigned short*)(w32 + xb_base);
        ull* seg = (ull*)(w32 + seg_base);

        (void)hipMemsetAsync(w32, 0, (bcnt_ints + 2) * sizeof(int), stream);

        int n4 = (N * 64) / 4;
        convert_x<<<(n4 + 255) / 256, 256, 0, stream>>>(x, xb, n4);

        int nbin = (E + 1023) / 1024;
        bin_edges<<<nbin, 256, 0, stream>>>(ei, ew, bcnt, seg, ovf_cnt, ovf, E);

        bucket_acc<<<NBK, 1024, 0, stream>>>(xb, bcnt, seg, out, N);
        ovf_apply<<<64, 256, 0, stream>>>(xb, ovf_cnt, ovf, out);
    } else {
        (void)hipMemsetAsync(out, 0, (size_t)out_size * sizeof(float), stream);
        long long threads = (long long)E * 16;
        scatter_edges<<<(int)((threads + 255) / 256), 256, 0, stream>>>(
            x, ei, ew, out, E);
    }
}

// Round 10
// 238.854 us; speedup vs baseline: 4.1085x; 3.5242x over previous
//
#include <hip/hip_runtime.h>
#include <hip/hip_fp16.h>
#include <stdint.h>

// LightGCNConv: out[row] += x[col] * edge_weight[e]
// x:[N,64] f32, edge_index:[2,E] int32, edge_weight:[E] f32, out:[N,64] f32.
//
// Pipeline:
//  1) bin_edges: append 8B entries (w | rl<<17 | col) into segment
//     (bucket=row>>7, class=blockIdx&7). Dense appends (measured <=25us).
//  2) csr_from_seg: one block per 128-row bucket; LDS *int* cursors
//     (native ds_add_rtn_u32); scatter 4B packed (col<<15|fp16w>>1) into the
//     bucket's 32KB padded-CSR window (one XCD's L2 -> ~1 writeback/line).
//     Replaces fill_padded's measured 83MB scattered writeback.
//  3) row_acc: one wave per row, 8-deep independent gathers (proven ~70us).

typedef unsigned long long ull;
typedef int   v4i __attribute__((ext_vector_type(4)));
typedef float v4f __attribute__((ext_vector_type(4)));

#define RB      128      // rows per bucket
#define NCLS    8        // segments per bucket
#define CAP     384      // entries per segment; mean ~256
#define SLOTS   64       // padded-CSR slots per row
#define OVF_CAP 65536

__device__ __forceinline__ unsigned short f2bf(float f) {
    union { float f; unsigned int u; } c;
    c.f = f;
    unsigned int lsb = (c.u >> 16) & 1u;
    c.u += 0x7fffu + lsb;
    return (unsigned short)(c.u >> 16);
}
__device__ __forceinline__ float bf2f(unsigned short u) {
    union { unsigned int u; float f; } c;
    c.u = ((unsigned int)u) << 16;
    return c.f;
}
__device__ __forceinline__ unsigned pack_cw(int col, float w) {
    unsigned hb = __half_as_ushort(__float2half(w));
    return (((unsigned)col) << 15) | (hb >> 1);
}
__device__ __forceinline__ float unpack_w(unsigned v) {
    return __half2float(__ushort_as_half((unsigned short)((v & 0x7fffu) << 1)));
}

// ---------- convert x -> bf16 ----------
__global__ __launch_bounds__(256) void convert_x(
    const float* __restrict__ x, unsigned short* __restrict__ xb, int n4)
{
    int i = blockIdx.x * 256 + threadIdx.x;
    if (i >= n4) return;
    v4f v = ((const v4f*)x)[i];
    ushort4 o;
    o.x = f2bf(v.x); o.y = f2bf(v.y); o.z = f2bf(v.z); o.w = f2bf(v.w);
    ((ushort4*)xb)[i] = o;
}

// ---------- phase 1: bin edges into (bucket,class) segments ----------
__device__ __forceinline__ void bin_one(
    int row, int col, float w, int cls,
    int* __restrict__ bcnt, ull* __restrict__ seg,
    int* __restrict__ ovf_cnt, int3* __restrict__ ovf)
{
    int b   = row >> 7;            // bucket (RB=128)
    int rl  = row & 127;
    int idx = b * NCLS + cls;
    int pos = atomicAdd(&bcnt[idx], 1);
    if (pos < CAP) {
        ull entry = (((ull)__float_as_uint(w)) << 32) |
                    (unsigned)((rl << 17) | col);
        seg[(size_t)idx * CAP + pos] = entry;
    } else {
        int o = atomicAdd(ovf_cnt, 1);
        if (o < OVF_CAP) ovf[o] = make_int3(row, col, __float_as_int(w));
    }
}

__global__ __launch_bounds__(256) void bin_edges(
    const int* __restrict__ ei, const float* __restrict__ ew,
    int* __restrict__ bcnt, ull* __restrict__ seg,
    int* __restrict__ ovf_cnt, int3* __restrict__ ovf, int E)
{
    int cls = blockIdx.x & 7;
    int e0 = blockIdx.x * 1024 + threadIdx.x * 4;
    if (e0 + 3 < E && (E & 3) == 0) {
        v4i r = __builtin_nontemporal_load((const v4i*)(ei + e0));
        v4i c = __builtin_nontemporal_load((const v4i*)(ei + E + e0));
        v4f w = __builtin_nontemporal_load((const v4f*)(ew + e0));
        bin_one(r.x, c.x, w.x, cls, bcnt, seg, ovf_cnt, ovf);
        bin_one(r.y, c.y, w.y, cls, bcnt, seg, ovf_cnt, ovf);
        bin_one(r.z, c.z, w.z, cls, bcnt, seg, ovf_cnt, ovf);
        bin_one(r.w, c.w, w.w, cls, bcnt, seg, ovf_cnt, ovf);
    } else {
        for (int e = e0; e < E && e < e0 + 4; ++e)
            bin_one(ei[e], ei[E + e], ew[e], cls, bcnt, seg, ovf_cnt, ovf);
    }
}

// ---------- phase 2: bucket segments -> padded CSR (LDS int cursors) ----------
__global__ __launch_bounds__(256) void csr_from_seg(
    const ull* __restrict__ seg, const int* __restrict__ bcnt,
    unsigned* __restrict__ csr4, int* __restrict__ cnt,
    int* __restrict__ ovf_cnt, int3* __restrict__ ovf, int N)
{
    __shared__ int cur[RB];
    int g = blockIdx.x;
    int t = threadIdx.x;
    if (t < RB) cur[t] = 0;
    __syncthreads();

    int row0 = g * RB;
    for (int cls = 0; cls < NCLS; ++cls) {
        int idx = g * NCLS + cls;
        int c = bcnt[idx];
        if (c > CAP) c = CAP;
        const ull* base = seg + (size_t)idx * CAP;
        for (int i = t; i < c; i += 256) {
            ull e = base[i];
            unsigned lo = (unsigned)e;
            float w = __int_as_float((int)(e >> 32));
            int rl  = (lo >> 17) & 127;
            int col = lo & 0x1FFFF;
            int pos = atomicAdd(&cur[rl], 1);      // native LDS int atomic
            if (pos < SLOTS) {
                csr4[(((size_t)(row0 + rl)) << 6) + pos] = pack_cw(col, w);
            } else {
                int o = atomicAdd(ovf_cnt, 1);
                if (o < OVF_CAP)
                    ovf[o] = make_int3(row0 + rl, col, __float_as_int(w));
            }
        }
    }
    __syncthreads();
    if (t < RB && row0 + t < N) cnt[row0 + t] = cur[t];
}

// ---------- phase 3: one wave per row, 8-deep pipelined gather ----------
template <bool BF>
__global__ __launch_bounds__(256) void row_acc(
    const void* __restrict__ xv, const int* __restrict__ cnt,
    const unsigned* __restrict__ csr4, float* __restrict__ out, int N)
{
    int row  = (blockIdx.x * 256 + threadIdx.x) >> 6;
    int lane = threadIdx.x & 63;
    if (row >= N) return;

    int c = cnt[row];
    if (c > SLOTS) c = SLOTS;
    const unsigned* base = csr4 + (((size_t)row) << 6);
    const unsigned short* xb = (const unsigned short*)xv;
    const float*          xf = (const float*)xv;

    float acc = 0.0f;
    int p = 0;
    for (; p + 8 <= c; p += 8) {
        unsigned a[8]; float xr[8];
#pragma unroll
        for (int i = 0; i < 8; ++i) a[i] = base[p + i];
#pragma unroll
        for (int i = 0; i < 8; ++i) {
            size_t off = (((size_t)(a[i] >> 15)) << 6) + lane;
            xr[i] = BF ? bf2f(xb[off]) : xf[off];
        }
#pragma unroll
        for (int i = 0; i < 8; ++i) acc = fmaf(xr[i], unpack_w(a[i]), acc);
    }
    if (p < c) {   // masked 8-group tail
        unsigned a[8]; float xr[8], w[8];
#pragma unroll
        for (int i = 0; i < 8; ++i) {
            int q = p + i;
            bool valid = q < c;
            if (!valid) q = c - 1;
            a[i] = base[q];
            w[i] = valid ? unpack_w(a[i]) : 0.0f;
        }
#pragma unroll
        for (int i = 0; i < 8; ++i) {
            size_t off = (((size_t)(a[i] >> 15)) << 6) + lane;
            xr[i] = BF ? bf2f(xb[off]) : xf[off];
        }
#pragma unroll
        for (int i = 0; i < 8; ++i) acc = fmaf(xr[i], w[i], acc);
    }
    __builtin_nontemporal_store(acc, out + (((size_t)row) << 6) + lane);
}

// ---------- overflow fixup (normally 0 edges) ----------
template <bool BF>
__global__ __launch_bounds__(256) void ovf_apply(
    const void* __restrict__ xv, const int* __restrict__ ovf_cnt,
    const int3* __restrict__ ovf, float* __restrict__ out)
{
    int n = *ovf_cnt;
    if (n > OVF_CAP) n = OVF_CAP;
    int wid  = (blockIdx.x * 256 + threadIdx.x) >> 6;
    int lane = threadIdx.x & 63;
    int nw   = gridDim.x * 4;
    for (int o = wid; o < n; o += nw) {
        int3 tt = ovf[o];
        float w = __int_as_float(tt.z);
        size_t off = (((size_t)tt.y) << 6) + lane;
        float x = BF ? bf2f(((const unsigned short*)xv)[off])
                     : ((const float*)xv)[off];
        atomicAdd(&out[(((size_t)tt.x) << 6) + lane], x * w);
    }
}

// ---------- fallback: direct atomic scatter ----------
__global__ __launch_bounds__(256) void scatter_edges(
    const float* __restrict__ x, const int* __restrict__ ei,
    const float* __restrict__ ew, float* __restrict__ out, int E)
{
    long long idx = (long long)blockIdx.x * 256 + threadIdx.x;
    int e = (int)(idx >> 4);
    if (e >= E) return;
    int j = (int)(idx & 15);
    int row = ei[e];
    int col = ei[E + e];
    float w = ew[e];
    v4f v = *(const v4f*)(x + (((size_t)col) << 6) + (j << 2));
    float* op = out + (((size_t)row) << 6) + (j << 2);
    atomicAdd(op + 0, v.x * w);
    atomicAdd(op + 1, v.y * w);
    atomicAdd(op + 2, v.z * w);
    atomicAdd(op + 3, v.w * w);
}

extern "C" void kernel_launch(void* const* d_in, const int* in_sizes, int n_in,
                              void* d_out, int out_size, void* d_ws, size_t ws_size,
                              hipStream_t stream) {
    const float* x  = (const float*)d_in[0];
    const int*   ei = (const int*)d_in[1];
    const float* ew = (const float*)d_in[2];
    float*       out = (float*)d_out;

    int E = in_sizes[2];
    int N = out_size / 64;
    int NBK = (N + RB - 1) / RB;

    // ws (ints): bcnt[NBK*8] | ovf_cnt | pad | ovf[3*OVF] | [xb N*32] |
    //            seg[NBK*8*CAP*2] | csr4[N*64] | cnt[N]
    size_t bcnt_ints = (size_t)NBK * NCLS;
    size_t ovf_base  = bcnt_ints + 2;
    size_t xb_base   = (ovf_base + 3 * (size_t)OVF_CAP + 3) & ~(size_t)3;
    size_t xb_ints   = (size_t)N * 32;
    size_t seg_ints  = (size_t)NBK * NCLS * CAP * 2;
    size_t csr_ints  = (size_t)N * SLOTS;

    size_t seg_base_bf = (xb_base + xb_ints + 1) & ~(size_t)1;
    size_t csr_base_bf = seg_base_bf + seg_ints;
    size_t cnt_base_bf = csr_base_bf + csr_ints;
    size_t need_bf     = (cnt_base_bf + (size_t)N) * 4;

    size_t seg_base_f  = (xb_base + 1) & ~(size_t)1;
    size_t csr_base_f  = seg_base_f + seg_ints;
    size_t cnt_base_f  = csr_base_f + csr_ints;
    size_t need_f      = (cnt_base_f + (size_t)N) * 4;

    int nbin = (E + 1023) / 1024;
    int acc_blocks = (N + 3) / 4;

    if ((ws_size >= need_bf || ws_size >= need_f) && N <= (1 << 17)) {
        bool use_bf = ws_size >= need_bf;
        int* w32 = (int*)d_ws;
        int* bcnt = w32;
        int* ovf_cnt = w32 + bcnt_ints;
        int3* ovf = (int3*)(w32 + ovf_base);
        unsigned short* xb = (unsigned short*)(w32 + xb_base);
        ull* seg = (ull*)(w32 + (use_bf ? seg_base_bf : seg_base_f));
        unsigned* csr4 = (unsigned*)(w32 + (use_bf ? csr_base_bf : csr_base_f));
        int* cnt = w32 + (use_bf ? cnt_base_bf : cnt_base_f);

        (void)hipMemsetAsync(w32, 0, (bcnt_ints + 2) * sizeof(int), stream);

        if (use_bf) {
            int n4 = (N * 64) / 4;
            convert_x<<<(n4 + 255) / 256, 256, 0, stream>>>(x, xb, n4);
        }
        bin_edges<<<nbin, 256, 0, stream>>>(ei, ew, bcnt, seg, ovf_cnt, ovf, E);
        csr_from_seg<<<NBK, 256, 0, stream>>>(seg, bcnt, csr4, cnt,
                                              ovf_cnt, ovf, N);
        if (use_bf) {
            row_acc<true><<<acc_blocks, 256, 0, stream>>>(xb, cnt, csr4, out, N);
            ovf_apply<true><<<64, 256, 0, stream>>>(xb, ovf_cnt, ovf, out);
        } else {
            row_acc<false><<<acc_blocks, 256, 0, stream>>>(x, cnt, csr4, out, N);
            ovf_apply<false><<<64, 256, 0, stream>>>(x, ovf_cnt, ovf, out);
        }
    } else {
        (void)hipMemsetAsync(out, 0, (size_t)out_size * sizeof(float), stream);
        long long threads = (long long)E * 16;
        scatter_edges<<<(int)((threads + 255) / 256), 256, 0, stream>>>(
            x, ei, ew, out, E);
    }
}

// Round 11
// 174.865 us; speedup vs baseline: 5.6120x; 1.3659x over previous
//
#include <hip/hip_runtime.h>
#include <hip/hip_fp16.h>
#include <stdint.h>

// LightGCNConv: out[row] += x[col] * edge_weight[e]
// x:[N,64] f32, edge_index:[2,E] int32, edge_weight:[E] f32, out:[N,64] f32.
//
// Pipeline:
//  1) bin_edges: counting-sort-style binning into 256-row buckets. Per block:
//     LDS histogram (fast ds_add_rtn) over 4096 edges, ONE global atomicAdd
//     per (block,bucket) to reserve a contiguous run, then dense run stores.
//     Replaces 1.6M global atomic reservations (measured ~80us floor across
//     4 variants) with ~150k, and 66MB writeback with ~20MB.
//  2) csr_from_seg: one block per bucket; LDS int cursors; scatter 4B packed
//     (col<<15|fp16w>>1) entries into the bucket's 64KB padded-CSR window.
//  3) row_acc: one wave per row, 8-deep independent bf16 gathers.

typedef unsigned long long ull;
typedef int   v4i __attribute__((ext_vector_type(4)));
typedef float v4f __attribute__((ext_vector_type(4)));

#define RB      256      // rows per bucket
#define CAP     4608     // entries per bucket segment; mean 4096 (+8 sigma)
#define CHUNK   4096     // edges per bin block (512 thr x 8)
#define SLOTS   64       // padded-CSR slots per row
#define OVF_CAP 65536
#define MAXNB   512      // max buckets (N <= 131072)

__device__ __forceinline__ unsigned short f2bf(float f) {
    union { float f; unsigned int u; } c;
    c.f = f;
    unsigned int lsb = (c.u >> 16) & 1u;
    c.u += 0x7fffu + lsb;
    return (unsigned short)(c.u >> 16);
}
__device__ __forceinline__ float bf2f(unsigned short u) {
    union { unsigned int u; float f; } c;
    c.u = ((unsigned int)u) << 16;
    return c.f;
}
__device__ __forceinline__ unsigned pack_cw(int col, float w) {
    unsigned hb = __half_as_ushort(__float2half(w));
    return (((unsigned)col) << 15) | (hb >> 1);
}
__device__ __forceinline__ float unpack_w(unsigned v) {
    return __half2float(__ushort_as_half((unsigned short)((v & 0x7fffu) << 1)));
}

// ---------- convert x -> bf16 ----------
__global__ __launch_bounds__(256) void convert_x(
    const float* __restrict__ x, unsigned short* __restrict__ xb, int n4)
{
    int i = blockIdx.x * 256 + threadIdx.x;
    if (i >= n4) return;
    v4f v = ((const v4f*)x)[i];
    ushort4 o;
    o.x = f2bf(v.x); o.y = f2bf(v.y); o.z = f2bf(v.z); o.w = f2bf(v.w);
    ((ushort4*)xb)[i] = o;
}

// ---------- phase 1: block-local counting-sort binning ----------
__global__ __launch_bounds__(512) void bin_edges(
    const int* __restrict__ ei, const float* __restrict__ ew,
    int* __restrict__ bcnt, ull* __restrict__ seg,
    int* __restrict__ ovf_cnt, int3* __restrict__ ovf, int E, int NB)
{
    __shared__ int hist[MAXNB];
    __shared__ int gbase[MAXNB];
    int t = threadIdx.x;
    for (int i = t; i < NB; i += 512) hist[i] = 0;
    __syncthreads();

    int e0 = blockIdx.x * CHUNK;

    unsigned pk[8];   // lpos<<9 | bkt
    ull      cw[8];   // w<<32 | rl<<17 | col
    bool     vd[8];
#pragma unroll
    for (int j = 0; j < 8; ++j) {
        int e = e0 + t + j * 512;
        vd[j] = e < E;
        int row = 0, col = 0; float w = 0.f;
        if (vd[j]) { row = ei[e]; col = ei[E + e]; w = ew[e]; }
        int bkt = row >> 8;
        int rl  = row & 255;
        int lp = 0;
        if (vd[j]) lp = atomicAdd(&hist[bkt], 1);   // LDS atomic: fast
        pk[j] = (((unsigned)lp) << 9) | (unsigned)bkt;
        cw[j] = (((ull)__float_as_uint(w)) << 32) |
                (unsigned)((rl << 17) | col);
    }
    __syncthreads();

    // one global reservation per (block,bucket)
    for (int i = t; i < NB; i += 512) {
        int h = hist[i];
        gbase[i] = h ? atomicAdd(&bcnt[i], h) : 0;
    }
    __syncthreads();

#pragma unroll
    for (int j = 0; j < 8; ++j) {
        if (!vd[j]) continue;
        int bkt = pk[j] & 511;
        int pos = gbase[bkt] + (int)(pk[j] >> 9);
        if (pos < CAP) {
            seg[(size_t)bkt * CAP + pos] = cw[j];
        } else {
            int o = atomicAdd(ovf_cnt, 1);
            if (o < OVF_CAP) {
                unsigned lo = (unsigned)cw[j];
                ovf[o] = make_int3((bkt << 8) | ((lo >> 17) & 255),
                                   lo & 0x1FFFF, (int)(cw[j] >> 32));
            }
        }
    }
}

// ---------- phase 2: bucket segment -> padded CSR (LDS int cursors) ----------
__global__ __launch_bounds__(512) void csr_from_seg(
    const ull* __restrict__ seg, const int* __restrict__ bcnt,
    unsigned* __restrict__ csr4, int* __restrict__ cnt,
    int* __restrict__ ovf_cnt, int3* __restrict__ ovf, int N)
{
    __shared__ int cur[RB];
    int g = blockIdx.x;
    int t = threadIdx.x;
    if (t < RB) cur[t] = 0;
    __syncthreads();

    int row0 = g * RB;
    int c = bcnt[g];
    if (c > CAP) c = CAP;
    const ull* base = seg + (size_t)g * CAP;
    for (int i = t; i < c; i += 512) {
        ull e = base[i];
        unsigned lo = (unsigned)e;
        int rl  = (lo >> 17) & 255;
        int col = lo & 0x1FFFF;
        float w = __int_as_float((int)(e >> 32));
        int pos = atomicAdd(&cur[rl], 1);          // native LDS int atomic
        if (pos < SLOTS) {
            csr4[(((size_t)(row0 + rl)) << 6) + pos] = pack_cw(col, w);
        } else {
            int o = atomicAdd(ovf_cnt, 1);
            if (o < OVF_CAP)
                ovf[o] = make_int3(row0 + rl, col, __float_as_int(w));
        }
    }
    __syncthreads();
    if (t < RB && row0 + t < N) {
        int v = cur[t];
        cnt[row0 + t] = v > SLOTS ? SLOTS : v;
    }
}

// ---------- phase 3: one wave per row, 8-deep pipelined gather ----------
template <bool BF>
__global__ __launch_bounds__(256) void row_acc(
    const void* __restrict__ xv, const int* __restrict__ cnt,
    const unsigned* __restrict__ csr4, float* __restrict__ out, int N)
{
    int row  = (blockIdx.x * 256 + threadIdx.x) >> 6;
    int lane = threadIdx.x & 63;
    if (row >= N) return;

    int c = cnt[row];
    if (c > SLOTS) c = SLOTS;
    const unsigned* base = csr4 + (((size_t)row) << 6);
    const unsigned short* xb = (const unsigned short*)xv;
    const float*          xf = (const float*)xv;

    float acc = 0.0f;
    int p = 0;
    for (; p + 8 <= c; p += 8) {
        unsigned a[8]; float xr[8];
#pragma unroll
        for (int i = 0; i < 8; ++i) a[i] = base[p + i];
#pragma unroll
        for (int i = 0; i < 8; ++i) {
            size_t off = (((size_t)(a[i] >> 15)) << 6) + lane;
            xr[i] = BF ? bf2f(xb[off]) : xf[off];
        }
#pragma unroll
        for (int i = 0; i < 8; ++i) acc = fmaf(xr[i], unpack_w(a[i]), acc);
    }
    if (p < c) {   // masked 8-group tail
        unsigned a[8]; float xr[8], w[8];
#pragma unroll
        for (int i = 0; i < 8; ++i) {
            int q = p + i;
            bool valid = q < c;
            if (!valid) q = c - 1;
            a[i] = base[q];
            w[i] = valid ? unpack_w(a[i]) : 0.0f;
        }
#pragma unroll
        for (int i = 0; i < 8; ++i) {
            size_t off = (((size_t)(a[i] >> 15)) << 6) + lane;
            xr[i] = BF ? bf2f(xb[off]) : xf[off];
        }
#pragma unroll
        for (int i = 0; i < 8; ++i) acc = fmaf(xr[i], w[i], acc);
    }
    __builtin_nontemporal_store(acc, out + (((size_t)row) << 6) + lane);
}

// ---------- overflow fixup (normally 0 edges) ----------
template <bool BF>
__global__ __launch_bounds__(256) void ovf_apply(
    const void* __restrict__ xv, const int* __restrict__ ovf_cnt,
    const int3* __restrict__ ovf, float* __restrict__ out)
{
    int n = *ovf_cnt;
    if (n > OVF_CAP) n = OVF_CAP;
    int wid  = (blockIdx.x * 256 + threadIdx.x) >> 6;
    int lane = threadIdx.x & 63;
    int nw   = gridDim.x * 4;
    for (int o = wid; o < n; o += nw) {
        int3 tt = ovf[o];
        float w = __int_as_float(tt.z);
        size_t off = (((size_t)tt.y) << 6) + lane;
        float x = BF ? bf2f(((const unsigned short*)xv)[off])
                     : ((const float*)xv)[off];
        atomicAdd(&out[(((size_t)tt.x) << 6) + lane], x * w);
    }
}

// ---------- fallback: direct atomic scatter ----------
__global__ __launch_bounds__(256) void scatter_edges(
    const float* __restrict__ x, const int* __restrict__ ei,
    const float* __restrict__ ew, float* __restrict__ out, int E)
{
    long long idx = (long long)blockIdx.x * 256 + threadIdx.x;
    int e = (int)(idx >> 4);
    if (e >= E) return;
    int j = (int)(idx & 15);
    int row = ei[e];
    int col = ei[E + e];
    float w = ew[e];
    v4f v = *(const v4f*)(x + (((size_t)col) << 6) + (j << 2));
    float* op = out + (((size_t)row) << 6) + (j << 2);
    atomicAdd(op + 0, v.x * w);
    atomicAdd(op + 1, v.y * w);
    atomicAdd(op + 2, v.z * w);
    atomicAdd(op + 3, v.w * w);
}

extern "C" void kernel_launch(void* const* d_in, const int* in_sizes, int n_in,
                              void* d_out, int out_size, void* d_ws, size_t ws_size,
                              hipStream_t stream) {
    const float* x  = (const float*)d_in[0];
    const int*   ei = (const int*)d_in[1];
    const float* ew = (const float*)d_in[2];
    float*       out = (float*)d_out;

    int E = in_sizes[2];
    int N = out_size / 64;
    int NB = (N + RB - 1) / RB;

    // ws (ints): bcnt[NB] | ovf_cnt | pad | ovf[3*OVF] | [xb N*32] |
    //            seg[NB*CAP*2] | csr4[N*64] | cnt[N]
    size_t ovf_base  = (size_t)NB + 2;
    size_t xb_base   = (ovf_base + 3 * (size_t)OVF_CAP + 3) & ~(size_t)3;
    size_t xb_ints   = (size_t)N * 32;
    size_t seg_ints  = (size_t)NB * CAP * 2;
    size_t csr_ints  = (size_t)N * SLOTS;

    size_t seg_base_bf = (xb_base + xb_ints + 1) & ~(size_t)1;
    size_t csr_base_bf = seg_base_bf + seg_ints;
    size_t cnt_base_bf = csr_base_bf + csr_ints;
    size_t need_bf     = (cnt_base_bf + (size_t)N) * 4;

    size_t seg_base_f  = (xb_base + 1) & ~(size_t)1;
    size_t csr_base_f  = seg_base_f + seg_ints;
    size_t cnt_base_f  = csr_base_f + csr_ints;
    size_t need_f      = (cnt_base_f + (size_t)N) * 4;

    int nbin = (E + CHUNK - 1) / CHUNK;
    int acc_blocks = (N + 3) / 4;

    if ((ws_size >= need_bf || ws_size >= need_f) && N <= (1 << 17)) {
        bool use_bf = ws_size >= need_bf;
        int* w32 = (int*)d_ws;
        int* bcnt = w32;
        int* ovf_cnt = w32 + NB;
        int3* ovf = (int3*)(w32 + ovf_base);
        unsigned short* xb = (unsigned short*)(w32 + xb_base);
        ull* seg = (ull*)(w32 + (use_bf ? seg_base_bf : seg_base_f));
        unsigned* csr4 = (unsigned*)(w32 + (use_bf ? csr_base_bf : csr_base_f));
        int* cnt = w32 + (use_bf ? cnt_base_bf : cnt_base_f);

        (void)hipMemsetAsync(w32, 0, ((size_t)NB + 2) * sizeof(int), stream);

        if (use_bf) {
            int n4 = (N * 64) / 4;
            convert_x<<<(n4 + 255) / 256, 256, 0, stream>>>(x, xb, n4);
        }
        bin_edges<<<nbin, 512, 0, stream>>>(ei, ew, bcnt, seg,
                                            ovf_cnt, ovf, E, NB);
        csr_from_seg<<<NB, 512, 0, stream>>>(seg, bcnt, csr4, cnt,
                                             ovf_cnt, ovf, N);
        if (use_bf) {
            row_acc<true><<<acc_blocks, 256, 0, stream>>>(xb, cnt, csr4, out, N);
            ovf_apply<true><<<64, 256, 0, stream>>>(xb, ovf_cnt, ovf, out);
        } else {
            row_acc<false><<<acc_blocks, 256, 0, stream>>>(x, cnt, csr4, out, N);
            ovf_apply<false><<<64, 256, 0, stream>>>(x, ovf_cnt, ovf, out);
        }
    } else {
        (void)hipMemsetAsync(out, 0, (size_t)out_size * sizeof(float), stream);
        long long threads = (long long)E * 16;
        scatter_edges<<<(int)((threads + 255) / 256), 256, 0, stream>>>(
            x, ei, ew, out, E);
    }
}